// Round 5
// baseline (996.955 us; speedup 1.0000x reference)
//
#include <hip/hip_runtime.h>
#include <hip/hip_bf16.h>
#include <math.h>

#define NB   16
#define CIN  128
#define COUT 128
#define HH   56
#define WW   56
#define LL   3136
#define NOC2 256

typedef __attribute__((ext_vector_type(8))) short short8;
typedef __attribute__((ext_vector_type(16))) float f32x16;
typedef __attribute__((ext_vector_type(4))) float f32x4;
typedef __attribute__((ext_vector_type(4))) unsigned int uint4v;

// ---- workspace layout (bytes) ----
#define CSD_OFF 256
#define WSP_OFF 32768
#define WL_OFF  (WSP_OFF + 2*9*NOC2*CIN*2)

#define TAU_A 3e-4f
#define TAU_B 3e-5f

// ---------------- prep: fp64 tables + folded/split weights ----------------
__global__ void prep_kernel(const float* __restrict__ w, const float* __restrict__ bk,
                            double* __restrict__ csd, unsigned short* __restrict__ wsp) {
    int i = blockIdx.x * 256 + threadIdx.x;
    if (i < 2*9*128) {
        int s = i / (9*128);
        int rem = i - s*(9*128);
        double v = (double)bk[rem];
        csd[i] = (s == 0) ? cos(v) : sin(v);
    }
    if (i < 9*128*128) {
        int k = i / (128*128);
        int rem = i - k*(128*128);
        int oc = rem >> 7, c = rem & 127;
        double bkv = (double)bk[k*128 + oc];
        float wv = w[i];
        float fa = (float)(cos(bkv) * (double)wv);
        float fb = (float)(sin(bkv) * (double)wv);
        __hip_bfloat16 ah = __float2bfloat16(fa);
        __hip_bfloat16 al = __float2bfloat16(fa - __bfloat162float(ah));
        __hip_bfloat16 bh = __float2bfloat16(fb);
        __hip_bfloat16 bl = __float2bfloat16(fb - __bfloat162float(bh));
        size_t base  = ((size_t)k*NOC2)*128;
        size_t lo    = (size_t)9*NOC2*128;
        wsp[base + (size_t)oc*128 + c]              = *(unsigned short*)&ah;
        wsp[base + (size_t)(128+oc)*128 + c]        = *(unsigned short*)&bh;
        wsp[lo + base + (size_t)oc*128 + c]         = *(unsigned short*)&al;
        wsp[lo + base + (size_t)(128+oc)*128 + c]   = *(unsigned short*)&bl;
    }
}

// ---------------- main MFMA kernel ----------------
#define PXT 128
#define NPXT 25
#define CP 24                 // ushort pitch per pixel/row: 16 ch + 8 pad (48 B)
#define XR 6
#define XC 58
#define XS_N (XR*XC*CP)       // 8352 ushort per (hi|lo)
#define WS_N (128*CP)         // 3072 ushort per (buf,hl)

__global__ __launch_bounds__(256)
void mfma_kernel(const float* __restrict__ x, const unsigned short* __restrict__ wsp,
                 const float* __restrict__ bias, float* __restrict__ out,
                 unsigned* __restrict__ cnt, unsigned* __restrict__ wl, unsigned cap)
{
    __shared__ __align__(16) unsigned short sm_x[2*XS_N];   // 33408 B (hi, lo)
    __shared__ __align__(16) unsigned short sm_w[4*WS_N];   // 24576 B [buf][hl]
    __shared__ float sm_bias[64];

    const int tid = threadIdx.x;
    int bid = blockIdx.x;
    const int ocb = bid & 1; bid >>= 1;
    const int pxt = bid % NPXT;
    const int bat = bid / NPXT;
    const int l0  = pxt * PXT;
    const int o0  = ocb * 64;
    const int y_first = l0 / WW;

    const int lane = tid & 63;
    const int n    = lane & 31;
    const int kh   = lane >> 5;
    const int wave = tid >> 6;
    const int wr   = wave >> 1;
    const int wpx  = wave & 1;

    const int p0 = l0 + wpx*64 + n;
    const int p1 = p0 + 32;
    int pc0 = p0 < LL ? p0 : LL-1;
    int pc1 = p1 < LL ? p1 : LL-1;
    int y0 = pc0 / WW, xx0 = pc0 - y0*WW;
    int y1 = pc1 / WW, xx1 = pc1 - y1*WW;
    const int pxb0 = ((y0 - y_first)*XC + xx0)*CP + kh*8;
    const int pxb1 = ((y1 - y_first)*XC + xx1)*CP + kh*8;
    const int iA   = (wr*32 + n)*CP + kh*8;

    // weight staging coords (same every tap)
    const int srow = tid >> 1;
    const int scg  = tid & 1;
    const int soc2 = (srow < 64) ? (o0 + srow) : (128 + o0 + (srow - 64));
    const int sd   = srow*CP + scg*8;

    if (tid < 64) sm_bias[tid] = bias[o0 + tid];

    f32x16 acc[4];  // [0]=a,px0 [1]=a,px1 [2]=b,px0 [3]=b,px1
    #pragma unroll
    for (int t = 0; t < 4; t++)
        #pragma unroll
        for (int r = 0; r < 16; r++) acc[t][r] = 0.f;

    const float* xb = x + (size_t)bat * CIN * LL;
    const size_t WLO = (size_t)9*NOC2*CIN;   // lo-table ushort offset

    for (int ch = 0; ch < 8; ch++) {
        const int c0 = ch * 16;
        __syncthreads();   // prior chunk's sm_x / sm_w readers done
        // stage x tile: 16 ch x 6 rows x 58 cols, hi/lo split
        for (int s = tid; s < 16*XR*XC; s += 256) {
            int cc  = s / (XR*XC);
            int rem = s - cc*(XR*XC);
            int r   = rem / XC;
            int col = rem - r*XC;
            int gr = y_first - 1 + r;
            int gc = col - 1;
            float v = 0.f;
            if ((unsigned)gr < HH && (unsigned)gc < WW)
                v = xb[(size_t)(c0+cc)*LL + gr*WW + gc];
            __hip_bfloat16 h = __float2bfloat16(v);
            __hip_bfloat16 l = __float2bfloat16(v - __bfloat162float(h));
            int off = (r*XC + col)*CP + cc;
            sm_x[off]        = *(unsigned short*)&h;
            sm_x[XS_N + off] = *(unsigned short*)&l;
        }
        // stage tap-0 weights into buf0
        {
            size_t g = ((size_t)soc2)*CIN + c0 + scg*8;   // tap 0
            uint4v h = *(const uint4v*)(wsp + g);
            uint4v l = *(const uint4v*)(wsp + WLO + g);
            *(uint4v*)&sm_w[sd]        = h;
            *(uint4v*)&sm_w[WS_N + sd] = l;
        }
        __syncthreads();

        #pragma unroll
        for (int tap = 0; tap < 9; tap++) {
            const int cur = tap & 1, nxt = cur ^ 1;
            // prefetch next tap's weights into registers (overlaps MFMAs)
            uint4v ph, pl;
            if (tap < 8) {
                size_t g = ((size_t)(tap+1)*NOC2 + soc2)*CIN + c0 + scg*8;
                ph = *(const uint4v*)(wsp + g);
                pl = *(const uint4v*)(wsp + WLO + g);
            }
            const int ky = tap / 3, kx = tap - 3*ky;
            const int to = (ky*XC + kx)*CP;
            const int wb = cur*2*WS_N;
            short8 Ah0 = *(const short8*)&sm_w[wb + iA];
            short8 Ah1 = *(const short8*)&sm_w[wb + iA + 64*CP];
            short8 Al0 = *(const short8*)&sm_w[wb + WS_N + iA];
            short8 Al1 = *(const short8*)&sm_w[wb + WS_N + iA + 64*CP];
            short8 Bh0 = *(const short8*)&sm_x[pxb0 + to];
            short8 Bh1 = *(const short8*)&sm_x[pxb1 + to];
            short8 Bl0 = *(const short8*)&sm_x[XS_N + pxb0 + to];
            short8 Bl1 = *(const short8*)&sm_x[XS_N + pxb1 + to];
            acc[0] = __builtin_amdgcn_mfma_f32_32x32x16_bf16(Al0, Bh0, acc[0], 0,0,0);
            acc[0] = __builtin_amdgcn_mfma_f32_32x32x16_bf16(Ah0, Bl0, acc[0], 0,0,0);
            acc[0] = __builtin_amdgcn_mfma_f32_32x32x16_bf16(Ah0, Bh0, acc[0], 0,0,0);
            acc[1] = __builtin_amdgcn_mfma_f32_32x32x16_bf16(Al0, Bh1, acc[1], 0,0,0);
            acc[1] = __builtin_amdgcn_mfma_f32_32x32x16_bf16(Ah0, Bl1, acc[1], 0,0,0);
            acc[1] = __builtin_amdgcn_mfma_f32_32x32x16_bf16(Ah0, Bh1, acc[1], 0,0,0);
            acc[2] = __builtin_amdgcn_mfma_f32_32x32x16_bf16(Al1, Bh0, acc[2], 0,0,0);
            acc[2] = __builtin_amdgcn_mfma_f32_32x32x16_bf16(Ah1, Bl0, acc[2], 0,0,0);
            acc[2] = __builtin_amdgcn_mfma_f32_32x32x16_bf16(Ah1, Bh0, acc[2], 0,0,0);
            acc[3] = __builtin_amdgcn_mfma_f32_32x32x16_bf16(Al1, Bh1, acc[3], 0,0,0);
            acc[3] = __builtin_amdgcn_mfma_f32_32x32x16_bf16(Ah1, Bl1, acc[3], 0,0,0);
            acc[3] = __builtin_amdgcn_mfma_f32_32x32x16_bf16(Ah1, Bh1, acc[3], 0,0,0);
            if (tap < 8) {
                int pd = nxt*2*WS_N + sd;
                *(uint4v*)&sm_w[pd]        = ph;
                *(uint4v*)&sm_w[WS_N + pd] = pl;
                __syncthreads();
            }
        }
    }

    // ---- epilogue: theta/magnitude in-register, transpose via LDS, x4 stores ----
    __syncthreads();                      // tap-8 sm_x readers done before overwrite
    float* conv_s = (float*)sm_x;         // 64 oc x 128 px floats = 32768 B (fits)
    const float eps = 1e-05f;
    const float PIf = 3.14159265358979323846f;
    size_t obase = (size_t)bat * (2*COUT) * LL;
    float ths[2][16];

    #pragma unroll
    for (int j = 0; j < 2; j++) {
        int p = j ? p1 : p0;
        #pragma unroll
        for (int r = 0; r < 16; r++) {
            int row = (r & 3) + 8*(r >> 2) + 4*kh;
            float av = acc[j][r];
            float bv = acc[2+j][r];
            if (p < LL && (fabsf(av) < TAU_A || fabsf(bv) < TAU_B)) {
                unsigned slot = atomicAdd(cnt, 1u);
                if (slot < cap)
                    wl[slot] = ((unsigned)(bat*LL + p) << 7) | (unsigned)(o0 + wr*32 + row);
            }
            bool ag = av > 0.f, bg = bv > 0.f;
            bool eq = (ag == bg);
            float ratio = eq ? (bv / (av + eps)) : (av / (bv + eps));
            float at = atanf(ratio);
            if (!eq) at = -at;
            float peak = eq ? (ag ? PIf*0.5f : -PIf*0.5f) : (bg ? 0.0f : -PIf);
            float th = peak - at;
            ths[j][r] = th;
            conv_s[(wr*32 + row)*PXT + (p - l0)] = sinf(th)*av + cosf(th)*bv + sm_bias[wr*32 + row];
        }
    }
    __syncthreads();
    #pragma unroll
    for (int i = 0; i < 8; i++) {
        int s = tid + 256*i;
        int row = s >> 5, seg = s & 31;
        int px0 = l0 + seg*4;
        if (px0 < LL)
            *(f32x4*)&out[obase + (size_t)(o0+row)*LL + px0] = *(const f32x4*)&conv_s[(row<<7) + (seg<<2)];
    }
    __syncthreads();
    #pragma unroll
    for (int j = 0; j < 2; j++) {
        int p = j ? p1 : p0;
        #pragma unroll
        for (int r = 0; r < 16; r++) {
            int row = (r & 3) + 8*(r >> 2) + 4*kh;
            conv_s[(wr*32 + row)*PXT + (p - l0)] = ths[j][r] * (1.0f/PIf);
        }
    }
    __syncthreads();
    #pragma unroll
    for (int i = 0; i < 8; i++) {
        int s = tid + 256*i;
        int row = s >> 5, seg = s & 31;
        int px0 = l0 + seg*4;
        if (px0 < LL)
            *(f32x4*)&out[obase + (size_t)(COUT+o0+row)*LL + px0] = *(const f32x4*)&conv_s[(row<<7) + (seg<<2)];
    }
}

// ---------------- fp64 fixup for near-discontinuity elements ----------------
__global__ __launch_bounds__(256)
void fixup_kernel(const float* __restrict__ x, const float* __restrict__ w,
                  const double* __restrict__ csd, const float* __restrict__ bias,
                  const unsigned* __restrict__ cnt, const unsigned* __restrict__ wl,
                  unsigned cap, float* __restrict__ out) {
    const int lane   = threadIdx.x & 63;
    const int waveid = (blockIdx.x * 256 + threadIdx.x) >> 6;
    const int nwaves = gridDim.x * 4;
    unsigned nf = *cnt; if (nf > cap) nf = cap;
    const double PI = 3.14159265358979323846;

    for (unsigned u = waveid; u < nf; u += nwaves) {
        unsigned idx = wl[u];
        int oc = idx & 127;
        unsigned rest = idx >> 7;
        int bb_ = rest / LL;
        int l   = rest - bb_*LL;
        int yy  = l / WW;
        int xx  = l - yy*WW;
        const float* xb = x + (size_t)bb_ * CIN * LL;

        double pa = 0.0, pb = 0.0;
        #pragma unroll
        for (int k = 0; k < 9; k++) {
            int dy = k/3, dx = k - dy*3;
            int py = yy + dy - 1, px = xx + dx - 1;
            double pk = 0.0;
            if ((unsigned)py < HH && (unsigned)px < WW) {
                int base = py*WW + px;
                const float* wr = w + k*(COUT*CIN) + oc*CIN;
                int c = lane;
                pk  = (double)xb[(size_t)c*LL + base] * (double)wr[c];
                c = lane + 64;
                pk += (double)xb[(size_t)c*LL + base] * (double)wr[c];
            }
            pa += csd[k*COUT + oc] * pk;
            pb += csd[9*COUT + k*COUT + oc] * pk;
        }
        #pragma unroll
        for (int off = 32; off > 0; off >>= 1) {
            pa += __shfl_xor(pa, off, 64);
            pb += __shfl_xor(pb, off, 64);
        }
        if (lane == 0) {
            bool ag = pa > 0.0, bg = pb > 0.0;
            bool eq = (ag == bg);
            double th;
            if (eq) th = (ag ? PI*0.5 : -PI*0.5) - atan(pb / (pa + 1e-5));
            else    th = (bg ? 0.0 : -PI) + atan(pa / (pb + 1e-5));
            double o = sin(th)*pa + cos(th)*pb + (double)bias[oc];
            out[((size_t)bb_*(2*COUT) + oc) * LL + l]        = (float)o;
            out[((size_t)bb_*(2*COUT) + COUT + oc) * LL + l] = (float)(th / PI);
        }
    }
}

extern "C" void kernel_launch(void* const* d_in, const int* in_sizes, int n_in,
                              void* d_out, int out_size, void* d_ws, size_t ws_size,
                              hipStream_t stream) {
    const float* x    = (const float*)d_in[0];
    const float* w    = (const float*)d_in[1];
    const float* bk   = (const float*)d_in[2];
    const float* bias = (const float*)d_in[3];
    float* out = (float*)d_out;

    char* ws = (char*)d_ws;
    unsigned*       cnt = (unsigned*)ws;
    double*         csd = (double*)(ws + CSD_OFF);
    unsigned short* wsp = (unsigned short*)(ws + WSP_OFF);
    unsigned*       wl  = (unsigned*)(ws + WL_OFF);
    unsigned cap = (ws_size > (size_t)WL_OFF + 4096) ? (unsigned)((ws_size - WL_OFF) / 4) : 0u;

    hipMemsetAsync(cnt, 0, 4, stream);
    hipLaunchKernelGGL(prep_kernel, dim3(576), dim3(256), 0, stream, w, bk, csd, wsp);
    hipLaunchKernelGGL(mfma_kernel, dim3(NB*NPXT*2), dim3(256), 0, stream,
                       x, wsp, bias, out, cnt, wl, cap);
    hipLaunchKernelGGL(fixup_kernel, dim3(512), dim3(256), 0, stream,
                       x, w, csd, bias, cnt, wl, cap, out);
}

// Round 6
// 445.410 us; speedup vs baseline: 2.2383x; 2.2383x over previous
//
#include <hip/hip_runtime.h>
#include <hip/hip_bf16.h>
#include <math.h>

#define NB   16
#define CIN  128
#define COUT 128
#define HH   56
#define WW   56
#define LL   3136
#define NOC2 256

typedef __attribute__((ext_vector_type(8))) short short8;
typedef __attribute__((ext_vector_type(16))) float f32x16;
typedef __attribute__((ext_vector_type(4))) float f32x4;
typedef __attribute__((ext_vector_type(4))) unsigned int uint4v;

// ---- workspace layout (bytes) ----
#define CSD_OFF 256
#define WSP_OFF 32768
#define WL_OFF  (WSP_OFF + 2*9*NOC2*CIN*2)

// ---------------- prep: fp64 tables + folded/split weights ----------------
__global__ void prep_kernel(const float* __restrict__ w, const float* __restrict__ bk,
                            double* __restrict__ csd, unsigned short* __restrict__ wsp) {
    int i = blockIdx.x * 256 + threadIdx.x;
    if (i < 2*9*128) {
        int s = i / (9*128);
        int rem = i - s*(9*128);
        double v = (double)bk[rem];
        csd[i] = (s == 0) ? cos(v) : sin(v);
    }
    if (i < 9*128*128) {
        int k = i / (128*128);
        int rem = i - k*(128*128);
        int oc = rem >> 7, c = rem & 127;
        double bkv = (double)bk[k*128 + oc];
        float wv = w[i];
        float fa = (float)(cos(bkv) * (double)wv);
        float fb = (float)(sin(bkv) * (double)wv);
        __hip_bfloat16 ah = __float2bfloat16(fa);
        __hip_bfloat16 al = __float2bfloat16(fa - __bfloat162float(ah));
        __hip_bfloat16 bh = __float2bfloat16(fb);
        __hip_bfloat16 bl = __float2bfloat16(fb - __bfloat162float(bh));
        size_t base  = ((size_t)k*NOC2)*128;
        size_t lo    = (size_t)9*NOC2*128;
        wsp[base + (size_t)oc*128 + c]              = *(unsigned short*)&ah;
        wsp[base + (size_t)(128+oc)*128 + c]        = *(unsigned short*)&bh;
        wsp[lo + base + (size_t)oc*128 + c]         = *(unsigned short*)&al;
        wsp[lo + base + (size_t)(128+oc)*128 + c]   = *(unsigned short*)&bl;
    }
}

// ---------------- main MFMA kernel ----------------
#define PXT 128
#define NPXT 25
#define CPX 24                // x pitch in ushorts (48 B) — 16-B aligned frags
#define XR 6
#define XC 58
#define XS_N (XR*XC*CPX)      // 8352 ushorts per (hi|lo)
#define CPW 16                // weight pitch in ushorts (32 B), xor-swizzled slots
#define WS_TAP (64*CPW)       // 1024 ushorts per tap per (hi|lo)
#define WS_N (9*WS_TAP)       // 9216 ushorts per (hi|lo)

__global__ __launch_bounds__(256, 2)
void mfma_kernel(const float* __restrict__ x, const unsigned short* __restrict__ wsp,
                 const float* __restrict__ bias, float* __restrict__ out,
                 unsigned* __restrict__ cnt, unsigned* __restrict__ wl, unsigned cap)
{
    __shared__ __align__(16) unsigned short sm_x[2*XS_N];   // 33408 B (hi, lo)
    __shared__ __align__(16) unsigned short sm_w[2*WS_N];   // 36864 B (hi, lo), all 9 taps
    __shared__ float sm_bias[32];

    const int tid = threadIdx.x;
    int bid = blockIdx.x;
    const int ocb = bid & 3; bid >>= 2;
    const int pxt = bid % NPXT;
    const int bat = bid / NPXT;
    const int l0  = pxt * PXT;
    const int o0  = ocb * 32;          // 32 output channels per block
    const int yf  = l0 / WW;

    const int lane = tid & 63;
    const int n    = lane & 31;
    const int kh   = lane >> 5;
    const int wave = tid >> 6;

    // this thread's pixel (MFMA column)
    const int p  = l0 + wave*32 + n;
    const int pc = p < LL ? p : LL-1;
    const int py = pc / WW, pxx = pc - py*WW;
    const int bB  = ((py - yf)*XC + pxx)*CPX + kh*8;
    const int sw  = ((((n>>2)&1) ^ kh) << 3);
    const int iAa = n*CPW + sw;          // a-rows 0..31
    const int iAb = (32+n)*CPW + sw;     // b-rows 32..63

    if (tid < 32) sm_bias[tid] = bias[o0 + tid];

    f32x16 acc_a, acc_b;
    #pragma unroll
    for (int r = 0; r < 16; r++) { acc_a[r] = 0.f; acc_b[r] = 0.f; }

    const float* xb = x + (size_t)bat * CIN * LL;
    const size_t WLO = (size_t)9*NOC2*CIN;

    for (int ch = 0; ch < 8; ch++) {
        const int c0 = ch * 16;
        __syncthreads();
        // ---- stage x tile: 16 ch x 6 rows x 58 cols, hi/lo, packed b32 writes ----
        for (int s = tid; s < 8*XR*XC; s += 256) {
            int ccp = s / (XR*XC);
            int rem = s - ccp*(XR*XC);
            int r   = rem / XC;
            int col = rem - r*XC;
            int gr = yf - 1 + r;
            int gc = col - 1;
            float v0 = 0.f, v1 = 0.f;
            if ((unsigned)gr < HH && (unsigned)gc < WW) {
                size_t g = (size_t)(c0 + 2*ccp)*LL + gr*WW + gc;
                v0 = xb[g];
                v1 = xb[g + LL];
            }
            __hip_bfloat16 h0 = __float2bfloat16(v0);
            __hip_bfloat16 h1 = __float2bfloat16(v1);
            __hip_bfloat16 l0b = __float2bfloat16(v0 - __bfloat162float(h0));
            __hip_bfloat16 l1b = __float2bfloat16(v1 - __bfloat162float(h1));
            unsigned hp = (unsigned)*(unsigned short*)&h0 | ((unsigned)*(unsigned short*)&h1 << 16);
            unsigned lp = (unsigned)*(unsigned short*)&l0b | ((unsigned)*(unsigned short*)&l1b << 16);
            int off = (r*XC + col)*CPX + 2*ccp;
            *(unsigned*)&sm_x[off]        = hp;
            *(unsigned*)&sm_x[XS_N + off] = lp;
        }
        // ---- stage ALL 9 taps' weights for this chunk (xor-swizzled 16B slots) ----
        for (int t = tid; t < 9*64*2; t += 256) {
            int tap = t >> 7;
            int rem = t & 127;
            int row = rem >> 1;
            int cg  = rem & 1;
            int oc2 = (row < 32) ? (o0 + row) : (128 + o0 + (row - 32));
            size_t g = ((size_t)tap*NOC2 + oc2)*CIN + c0 + cg*8;
            uint4v hv = *(const uint4v*)(wsp + g);
            uint4v lv = *(const uint4v*)(wsp + WLO + g);
            int dst = tap*WS_TAP + row*CPW + ((cg ^ ((row>>2)&1)) << 3);
            *(uint4v*)&sm_w[dst]        = hv;
            *(uint4v*)&sm_w[WS_N + dst] = lv;
        }
        __syncthreads();

        #pragma unroll
        for (int tap = 0; tap < 9; tap++) {
            const int ky = tap / 3, kx = tap - 3*ky;
            const int to = (ky*XC + kx)*CPX;
            const int wb = tap*WS_TAP;
            short8 Aha = *(const short8*)&sm_w[wb + iAa];
            short8 Ahb = *(const short8*)&sm_w[wb + iAb];
            short8 Ala = *(const short8*)&sm_w[WS_N + wb + iAa];
            short8 Alb = *(const short8*)&sm_w[WS_N + wb + iAb];
            short8 Bh  = *(const short8*)&sm_x[bB + to];
            short8 Bl  = *(const short8*)&sm_x[XS_N + bB + to];
            acc_a = __builtin_amdgcn_mfma_f32_32x32x16_bf16(Ala, Bh, acc_a, 0,0,0);
            acc_a = __builtin_amdgcn_mfma_f32_32x32x16_bf16(Aha, Bl, acc_a, 0,0,0);
            acc_a = __builtin_amdgcn_mfma_f32_32x32x16_bf16(Aha, Bh, acc_a, 0,0,0);
            acc_b = __builtin_amdgcn_mfma_f32_32x32x16_bf16(Alb, Bh, acc_b, 0,0,0);
            acc_b = __builtin_amdgcn_mfma_f32_32x32x16_bf16(Ahb, Bl, acc_b, 0,0,0);
            acc_b = __builtin_amdgcn_mfma_f32_32x32x16_bf16(Ahb, Bh, acc_b, 0,0,0);
        }
    }

    // ---- epilogue: theta/magnitude, transpose via LDS, x4 stores ----
    __syncthreads();
    float* conv_s  = (float*)sm_x;           // 32 x 128 floats = 16 KB
    float* theta_s = conv_s + 32*PXT;        // 16 KB (total 32 KB <= 33.4 KB)
    const float eps = 1e-05f;
    const float PIf = 3.14159265358979323846f;
    const int pcol = wave*32 + n;            // p - l0

    #pragma unroll
    for (int r = 0; r < 16; r++) {
        int row = (r & 3) + 8*(r >> 2) + 4*kh;
        float av = acc_a[r];
        float bv = acc_b[r];
        // flag near-discontinuity elements (covers b=0 and b=-eps lines)
        bool flag = (p < LL) &&
                    (fabsf(av) < 1.5e-4f || (bv < 1.05e-5f && bv > -2.05e-5f));
        unsigned long long m = __ballot(flag);
        if (m) {
            int leader = (int)__ffsll((long long)m) - 1;
            unsigned base = 0;
            if (lane == leader) base = atomicAdd(cnt, (unsigned)__popcll(m));
            base = __shfl(base, leader);
            if (flag) {
                unsigned slot = base + (unsigned)__popcll(m & ((1ULL << lane) - 1ULL));
                if (slot < cap)
                    wl[slot] = ((unsigned)(bat*LL + p) << 7) | (unsigned)(o0 + row);
            }
        }
        bool ag = av > 0.f, bg = bv > 0.f;
        bool eq = (ag == bg);
        float ratio = eq ? (bv / (av + eps)) : (av / (bv + eps));
        float at = atanf(ratio);
        if (!eq) at = -at;
        float peak = eq ? (ag ? PIf*0.5f : -PIf*0.5f) : (bg ? 0.0f : -PIf);
        float th = peak - at;
        conv_s[row*PXT + pcol]  = sinf(th)*av + cosf(th)*bv + sm_bias[row];
        theta_s[row*PXT + pcol] = th * (1.0f/PIf);
    }
    __syncthreads();
    size_t obase = (size_t)bat * (2*COUT) * LL;
    #pragma unroll
    for (int i = 0; i < 4; i++) {
        int s = tid + 256*i;
        int row = s >> 5, seg = s & 31;
        int px0 = l0 + seg*4;
        if (px0 < LL)
            *(f32x4*)&out[obase + (size_t)(o0+row)*LL + px0] = *(const f32x4*)&conv_s[(row<<7) + (seg<<2)];
    }
    #pragma unroll
    for (int i = 0; i < 4; i++) {
        int s = tid + 256*i;
        int row = s >> 5, seg = s & 31;
        int px0 = l0 + seg*4;
        if (px0 < LL)
            *(f32x4*)&out[obase + (size_t)(COUT+o0+row)*LL + px0] = *(const f32x4*)&theta_s[(row<<7) + (seg<<2)];
    }
}

// ---------------- fp64 fixup for near-discontinuity elements ----------------
__global__ __launch_bounds__(256)
void fixup_kernel(const float* __restrict__ x, const float* __restrict__ w,
                  const double* __restrict__ csd, const float* __restrict__ bias,
                  const unsigned* __restrict__ cnt, const unsigned* __restrict__ wl,
                  unsigned cap, float* __restrict__ out) {
    const int lane   = threadIdx.x & 63;
    const int waveid = (blockIdx.x * 256 + threadIdx.x) >> 6;
    const int nwaves = gridDim.x * 4;
    unsigned nf = *cnt; if (nf > cap) nf = cap;
    const double PI = 3.14159265358979323846;

    for (unsigned u = waveid; u < nf; u += nwaves) {
        unsigned idx = wl[u];
        int oc = idx & 127;
        unsigned rest = idx >> 7;
        int bb_ = rest / LL;
        int l   = rest - bb_*LL;
        int yy  = l / WW;
        int xx  = l - yy*WW;
        const float* xb = x + (size_t)bb_ * CIN * LL;

        double pa = 0.0, pb = 0.0;
        #pragma unroll
        for (int k = 0; k < 9; k++) {
            int dy = k/3, dx = k - dy*3;
            int py = yy + dy - 1, px = xx + dx - 1;
            double pk = 0.0;
            if ((unsigned)py < HH && (unsigned)px < WW) {
                int base = py*WW + px;
                const float* wr = w + k*(COUT*CIN) + oc*CIN;
                int c = lane;
                pk  = (double)xb[(size_t)c*LL + base] * (double)wr[c];
                c = lane + 64;
                pk += (double)xb[(size_t)c*LL + base] * (double)wr[c];
            }
            pa += csd[k*COUT + oc] * pk;
            pb += csd[9*COUT + k*COUT + oc] * pk;
        }
        #pragma unroll
        for (int off = 32; off > 0; off >>= 1) {
            pa += __shfl_xor(pa, off, 64);
            pb += __shfl_xor(pb, off, 64);
        }
        if (lane == 0) {
            bool ag = pa > 0.0, bg = pb > 0.0;
            bool eq = (ag == bg);
            double th;
            if (eq) th = (ag ? PI*0.5 : -PI*0.5) - atan(pb / (pa + 1e-5));
            else    th = (bg ? 0.0 : -PI) + atan(pa / (pb + 1e-5));
            double o = sin(th)*pa + cos(th)*pb + (double)bias[oc];
            out[((size_t)bb_*(2*COUT) + oc) * LL + l]        = (float)o;
            out[((size_t)bb_*(2*COUT) + COUT + oc) * LL + l] = (float)(th / PI);
        }
    }
}

extern "C" void kernel_launch(void* const* d_in, const int* in_sizes, int n_in,
                              void* d_out, int out_size, void* d_ws, size_t ws_size,
                              hipStream_t stream) {
    const float* x    = (const float*)d_in[0];
    const float* w    = (const float*)d_in[1];
    const float* bk   = (const float*)d_in[2];
    const float* bias = (const float*)d_in[3];
    float* out = (float*)d_out;

    char* ws = (char*)d_ws;
    unsigned*       cnt = (unsigned*)ws;
    double*         csd = (double*)(ws + CSD_OFF);
    unsigned short* wsp = (unsigned short*)(ws + WSP_OFF);
    unsigned*       wl  = (unsigned*)(ws + WL_OFF);
    unsigned cap = (ws_size > (size_t)WL_OFF + 4096) ? (unsigned)((ws_size - WL_OFF) / 4) : 0u;

    hipMemsetAsync(cnt, 0, 4, stream);
    hipLaunchKernelGGL(prep_kernel, dim3(576), dim3(256), 0, stream, w, bk, csd, wsp);
    hipLaunchKernelGGL(mfma_kernel, dim3(NB*NPXT*4), dim3(256), 0, stream,
                       x, wsp, bias, out, cnt, wl, cap);
    hipLaunchKernelGGL(fixup_kernel, dim3(512), dim3(256), 0, stream,
                       x, w, csd, bias, cnt, wl, cap, out);
}